// Round 1
// baseline (119.215 us; speedup 1.0000x reference)
//
#include <hip/hip_runtime.h>

// WMAE: out = sum_{i,j} w[j] * |t1[i,j] - t2[i,j]| / n_sample
// t1,t2: fp32 [4194304, 3] row-major. w = {300, 1, 200}.
//
// R7 theory: top-5 rocprof dispatches are ALL harness poison fills (256 MiB
// @ 42us, 80% HBM peak) -> our kernels are <41us each; most of the 114us
// metric is harness-side. Kernel floor = 100.7 MB compulsory / 6.4 TB/s
// (fill-demonstrated) = 15.7us. Levers: (1) revert R6's 8192x128 geometry
// (regressed 113.16->114.17) to 4096x256x3; (2) non-temporal streaming
// loads (inputs are read-once, poison fill evicts L3 every iter anyway);
// (3) single-wave float4 finish (no smem/sync).

#define THREADS 256
#define CPT 3                                // float4 chunks per thread
#define CHUNKS_PER_BLOCK (THREADS * CPT)     // 768
#define P1_BLOCKS 4096                       // 4096 * 768 = 3145728 chunks exactly

typedef float v4f __attribute__((ext_vector_type(4)));

__device__ __forceinline__ float3 wsel(int r) {
    // weights for features (r, r+1, r+2) mod 3, where w = {300, 1, 200}
    float w0 = (r == 0) ? 300.0f : ((r == 1) ? 1.0f : 200.0f);
    float w1 = (r == 0) ? 1.0f   : ((r == 1) ? 200.0f : 300.0f);
    float w2 = (r == 0) ? 200.0f : ((r == 1) ? 300.0f : 1.0f);
    return make_float3(w0, w1, w2);
}

__global__ __launch_bounds__(THREADS, 8) void wmae_partial(
    const v4f* __restrict__ t1, const v4f* __restrict__ t2,
    float* __restrict__ partials, float inv_n) {
    const int base = blockIdx.x * CHUNKS_PER_BLOCK + threadIdx.x;

    // streaming (non-temporal) loads: read-once data, don't allocate in L2/L3
    v4f a[CPT], b[CPT];
    #pragma unroll
    for (int k = 0; k < CPT; ++k)
        a[k] = __builtin_nontemporal_load(&t1[base + k * THREADS]);
    #pragma unroll
    for (int k = 0; k < CPT; ++k)
        b[k] = __builtin_nontemporal_load(&t2[base + k * THREADS]);

    float acc = 0.0f;
    int r = base % 3;  // chunk base elem = 4*i, 4 == 1 (mod 3)
    #pragma unroll
    for (int k = 0; k < CPT; ++k) {
        float3 w = wsel(r);
        acc += w.x * (fabsf(a[k].x - b[k].x) + fabsf(a[k].w - b[k].w))
             + w.y *  fabsf(a[k].y - b[k].y)
             + w.z *  fabsf(a[k].z - b[k].z);
        r = (r + 1) % 3;   // +256 chunks == +1 (mod 3)
    }

    // wave-64 shuffle reduction (4 waves/block)
    #pragma unroll
    for (int off = 32; off > 0; off >>= 1)
        acc += __shfl_down(acc, off, 64);
    __shared__ float smem[THREADS / 64];
    const int wave = threadIdx.x >> 6;
    const int lane = threadIdx.x & 63;
    if (lane == 0) smem[wave] = acc;
    __syncthreads();
    if (threadIdx.x == 0)
        partials[blockIdx.x] = (smem[0] + smem[1] + smem[2] + smem[3]) * inv_n;
}

__global__ __launch_bounds__(64) void wmae_finish(
    const v4f* __restrict__ partials4, float* __restrict__ out) {
    // 4096 partial floats = 1024 float4; 64 lanes x 16 each, coalesced.
    float acc = 0.0f;
    #pragma unroll
    for (int k = 0; k < P1_BLOCKS / 4 / 64; ++k) {
        v4f v = partials4[k * 64 + threadIdx.x];
        acc += (v.x + v.y) + (v.z + v.w);
    }
    #pragma unroll
    for (int off = 32; off > 0; off >>= 1)
        acc += __shfl_down(acc, off, 64);
    if (threadIdx.x == 0)
        out[0] = acc;
}

extern "C" void kernel_launch(void* const* d_in, const int* in_sizes, int n_in,
                              void* d_out, int out_size, void* d_ws, size_t ws_size,
                              hipStream_t stream) {
    const v4f* t1 = (const v4f*)d_in[0];
    const v4f* t2 = (const v4f*)d_in[1];
    float* out = (float*)d_out;
    float* partials = (float*)d_ws;            // 4096 floats, fully overwritten

    const int n_elems = in_sizes[0];           // 12582912
    const int n_sample = n_elems / 3;          // 4194304
    const float inv_n = 1.0f / (float)n_sample;

    wmae_partial<<<P1_BLOCKS, THREADS, 0, stream>>>(t1, t2, partials, inv_n);
    wmae_finish<<<1, 64, 0, stream>>>((const v4f*)partials, out);
}

// Round 2
// 112.190 us; speedup vs baseline: 1.0626x; 1.0626x over previous
//
#include <hip/hip_runtime.h>

// WMAE: out = sum_{i,j} w[j] * |t1[i,j] - t2[i,j]| / n_sample
// t1,t2: fp32 [4194304, 3] row-major. w = {300, 1, 200}.
//
// R8: R7 post-mortem — nontemporal loads cost +6us (nt bypasses L2
// allocation; read streams want normal cached loads, unlike the write-only
// poison fill that hits 6.5 TB/s). Revert to plain loads. Keep R7's
// 4096x256x3 geometry (R4's 113.16us balance point) and the single-wave
// float4 finish kernel (no smem/syncthreads on the 1-block dispatch).

#define THREADS 256
#define CPT 3                                // float4 chunks per thread
#define CHUNKS_PER_BLOCK (THREADS * CPT)     // 768
#define P1_BLOCKS 4096                       // 4096 * 768 = 3145728 chunks exactly

typedef float v4f __attribute__((ext_vector_type(4)));

__device__ __forceinline__ float3 wsel(int r) {
    // weights for features (r, r+1, r+2) mod 3, where w = {300, 1, 200}
    float w0 = (r == 0) ? 300.0f : ((r == 1) ? 1.0f : 200.0f);
    float w1 = (r == 0) ? 1.0f   : ((r == 1) ? 200.0f : 300.0f);
    float w2 = (r == 0) ? 200.0f : ((r == 1) ? 300.0f : 1.0f);
    return make_float3(w0, w1, w2);
}

__global__ __launch_bounds__(THREADS, 8) void wmae_partial(
    const v4f* __restrict__ t1, const v4f* __restrict__ t2,
    float* __restrict__ partials, float inv_n) {
    const int base = blockIdx.x * CHUNKS_PER_BLOCK + threadIdx.x;

    v4f a[CPT], b[CPT];
    #pragma unroll
    for (int k = 0; k < CPT; ++k) a[k] = t1[base + k * THREADS];
    #pragma unroll
    for (int k = 0; k < CPT; ++k) b[k] = t2[base + k * THREADS];

    float acc = 0.0f;
    int r = base % 3;  // chunk base elem = 4*i, 4 == 1 (mod 3)
    #pragma unroll
    for (int k = 0; k < CPT; ++k) {
        float3 w = wsel(r);
        acc += w.x * (fabsf(a[k].x - b[k].x) + fabsf(a[k].w - b[k].w))
             + w.y *  fabsf(a[k].y - b[k].y)
             + w.z *  fabsf(a[k].z - b[k].z);
        r = (r + 1) % 3;   // +256 chunks == +1 (mod 3)
    }

    // wave-64 shuffle reduction (4 waves/block)
    #pragma unroll
    for (int off = 32; off > 0; off >>= 1)
        acc += __shfl_down(acc, off, 64);
    __shared__ float smem[THREADS / 64];
    const int wave = threadIdx.x >> 6;
    const int lane = threadIdx.x & 63;
    if (lane == 0) smem[wave] = acc;
    __syncthreads();
    if (threadIdx.x == 0)
        partials[blockIdx.x] = (smem[0] + smem[1] + smem[2] + smem[3]) * inv_n;
}

__global__ __launch_bounds__(64) void wmae_finish(
    const v4f* __restrict__ partials4, float* __restrict__ out) {
    // 4096 partial floats = 1024 float4; 64 lanes x 16 each, coalesced.
    float acc = 0.0f;
    #pragma unroll
    for (int k = 0; k < P1_BLOCKS / 4 / 64; ++k) {
        v4f v = partials4[k * 64 + threadIdx.x];
        acc += (v.x + v.y) + (v.z + v.w);
    }
    #pragma unroll
    for (int off = 32; off > 0; off >>= 1)
        acc += __shfl_down(acc, off, 64);
    if (threadIdx.x == 0)
        out[0] = acc;
}

extern "C" void kernel_launch(void* const* d_in, const int* in_sizes, int n_in,
                              void* d_out, int out_size, void* d_ws, size_t ws_size,
                              hipStream_t stream) {
    const v4f* t1 = (const v4f*)d_in[0];
    const v4f* t2 = (const v4f*)d_in[1];
    float* out = (float*)d_out;
    float* partials = (float*)d_ws;            // 4096 floats, fully overwritten

    const int n_elems = in_sizes[0];           // 12582912
    const int n_sample = n_elems / 3;          // 4194304
    const float inv_n = 1.0f / (float)n_sample;

    wmae_partial<<<P1_BLOCKS, THREADS, 0, stream>>>(t1, t2, partials, inv_n);
    wmae_finish<<<1, 64, 0, stream>>>((const v4f*)partials, out);
}